// Round 1
// baseline (100.701 us; speedup 1.0000x reference)
//
#include <hip/hip_runtime.h>
#include <math.h>

#define B 2
#define T 4096
#define H 8
#define E 64
#define D 64
#define C 128          // chunk length
#define NC (T / C)     // 32 chunks
#define BH (B * H)     // 16
#define EPS 1e-6f

__device__ __forceinline__ float phi(float x) {
    // elu(x) + 1
    return x > 0.0f ? x + 1.0f : expf(x);
}

// ---------------- Kernel 1: per-chunk partial sums ----------------
// S_part[bh,c][e][d] = sum_{t in chunk} phi(K_t[e]) * V_t[d]
// z_part[bh,c][e]    = sum_{t in chunk} phi(K_t[e])
__global__ __launch_bounds__(256) void k_chunk_sums(
        const float* __restrict__ Kg, const float* __restrict__ Vg,
        float* __restrict__ Spart, float* __restrict__ zpart) {
    int blk = blockIdx.x;           // bh * NC + c
    int bh = blk / NC, c = blk % NC;
    int b = bh / H, h = bh % H;
    int t0 = c * C;
    __shared__ float sK[C][E + 1];
    __shared__ float sV[C][E + 1];
    int tid = threadIdx.x;

    for (int l = tid; l < C * E; l += 256) {
        int i = l >> 6, e = l & 63;
        size_t g = ((size_t)(b * T + t0 + i) * H + h) * E + e;
        sK[i][e] = phi(Kg[g]);
        sV[i][e] = Vg[g];
    }
    __syncthreads();

    // 64x64 outputs, 256 threads -> 4x4 tile per thread (16x16 thread grid)
    int ty = tid >> 4, tx = tid & 15;
    int e0 = ty * 4, d0 = tx * 4;
    float acc[4][4] = {};
    for (int t = 0; t < C; ++t) {
        float a[4], v[4];
        #pragma unroll
        for (int u = 0; u < 4; ++u) a[u] = sK[t][e0 + u];
        #pragma unroll
        for (int u = 0; u < 4; ++u) v[u] = sV[t][d0 + u];
        #pragma unroll
        for (int u = 0; u < 4; ++u)
            #pragma unroll
            for (int w = 0; w < 4; ++w)
                acc[u][w] += a[u] * v[w];
    }
    float* Sp = Spart + (size_t)blk * (E * D);
    #pragma unroll
    for (int u = 0; u < 4; ++u)
        #pragma unroll
        for (int w = 0; w < 4; ++w)
            Sp[(e0 + u) * D + (d0 + w)] = acc[u][w];

    if (tid < E) {
        float s = 0.0f;
        for (int t = 0; t < C; ++t) s += sK[t][tid];
        zpart[(size_t)blk * E + tid] = s;
    }
}

// ---------------- Kernel 2: exclusive prefix scan over chunks (in place) ----
__global__ __launch_bounds__(256) void k_scan(
        float* __restrict__ Spart, float* __restrict__ zpart) {
    int bh  = blockIdx.x / 17;
    int sub = blockIdx.x % 17;
    int tid = threadIdx.x;
    if (sub < 16) {
        int l = sub * 256 + tid;   // element index within 64x64
        float run = 0.0f;
        float* base = Spart + (size_t)bh * NC * (E * D) + l;
        for (int c = 0; c < NC; ++c) {
            float t = base[(size_t)c * (E * D)];
            base[(size_t)c * (E * D)] = run;
            run += t;
        }
    } else if (tid < E) {
        float run = 0.0f;
        float* base = zpart + (size_t)bh * NC * E + tid;
        for (int c = 0; c < NC; ++c) {
            float t = base[(size_t)c * E];
            base[(size_t)c * E] = run;
            run += t;
        }
    }
}

// ---------------- Kernel 3: per-chunk output ----------------
// out_i = phiQ_i @ S0 + sum_{j<=i} (phiQ_i . phiK_j) * V_j
// den_i = phiQ_i . z0 + sum_{j<=i} (phiQ_i . phiK_j)
__global__ __launch_bounds__(256) void k_output(
        const float* __restrict__ Qg, const float* __restrict__ Kg,
        const float* __restrict__ Vg, const float* __restrict__ Spart,
        const float* __restrict__ zpart, float* __restrict__ Og) {
    int blk = blockIdx.x;
    int bh = blk / NC, c = blk % NC;
    int b = bh / H, h = bh % H;
    int t0 = c * C;
    __shared__ float sQ[C][E + 1];     // phi(Q)
    __shared__ float sKV[C][E + 1];    // phi(K), later V
    __shared__ float sA[C][C + 1];     // masked scores
    __shared__ float sS0[E][D + 1];    // prefix state
    __shared__ float sDen[C];
    int tid = threadIdx.x;

    for (int l = tid; l < C * E; l += 256) {
        int i = l >> 6, e = l & 63;
        size_t g = ((size_t)(b * T + t0 + i) * H + h) * E + e;
        sQ[i][e]  = phi(Qg[g]);
        sKV[i][e] = phi(Kg[g]);
    }
    const float* Sp = Spart + (size_t)blk * (E * D);
    for (int l = tid; l < E * D; l += 256)
        sS0[l >> 6][l & 63] = Sp[l];
    __syncthreads();

    // scores: 128x128, 8x8 tile per thread (16x16 grid); skip fully-masked tiles
    int ty = tid >> 4, tx = tid & 15;
    int i0 = ty * 8, j0 = tx * 8;
    {
        float acc[8][8] = {};
        if (tx <= ty) {   // tile touches j <= i region
            for (int e = 0; e < E; ++e) {
                float qa[8], kb[8];
                #pragma unroll
                for (int u = 0; u < 8; ++u) qa[u] = sQ[i0 + u][e];
                #pragma unroll
                for (int u = 0; u < 8; ++u) kb[u] = sKV[j0 + u][e];
                #pragma unroll
                for (int u = 0; u < 8; ++u)
                    #pragma unroll
                    for (int w = 0; w < 8; ++w)
                        acc[u][w] += qa[u] * kb[w];
            }
        }
        #pragma unroll
        for (int u = 0; u < 8; ++u)
            #pragma unroll
            for (int w = 0; w < 8; ++w) {
                int i = i0 + u, j = j0 + w;
                sA[i][j] = (j <= i) ? acc[u][w] : 0.0f;
            }
    }
    __syncthreads();

    // overwrite sKV with V (everyone past barrier, K no longer needed)
    for (int l = tid; l < C * E; l += 256) {
        int i = l >> 6, e = l & 63;
        size_t g = ((size_t)(b * T + t0 + i) * H + h) * E + e;
        sKV[i][e] = Vg[g];
    }
    // denominators (threads 0..127), runs concurrently with V load
    if (tid < C) {
        const float* zp = zpart + (size_t)blk * E;
        float s = 0.0f;
        for (int e = 0; e < E; ++e) s += sQ[tid][e] * zp[e];
        for (int j = 0; j < C; ++j) s += sA[tid][j];
        sDen[tid] = s;
    }
    __syncthreads();

    // out tile: 8 rows x 4 cols per thread
    {
        int d0 = tx * 4;
        float acc[8][4] = {};
        for (int e = 0; e < E; ++e) {
            float s0[4];
            #pragma unroll
            for (int w = 0; w < 4; ++w) s0[w] = sS0[e][d0 + w];
            #pragma unroll
            for (int u = 0; u < 8; ++u) {
                float q = sQ[i0 + u][e];
                #pragma unroll
                for (int w = 0; w < 4; ++w) acc[u][w] += q * s0[w];
            }
        }
        int jmax = i0 + 8;   // rows i0..i0+7 only need j <= i0+7
        for (int j = 0; j < jmax; ++j) {
            float v[4];
            #pragma unroll
            for (int w = 0; w < 4; ++w) v[w] = sKV[j][d0 + w];
            #pragma unroll
            for (int u = 0; u < 8; ++u) {
                float a = sA[i0 + u][j];
                #pragma unroll
                for (int w = 0; w < 4; ++w) acc[u][w] += a * v[w];
            }
        }
        #pragma unroll
        for (int u = 0; u < 8; ++u) {
            int i = i0 + u;
            float zi = 1.0f / (sDen[i] + EPS);
            size_t g = ((size_t)(b * T + t0 + i) * H + h) * D + d0;
            #pragma unroll
            for (int w = 0; w < 4; ++w) Og[g + w] = acc[u][w] * zi;
        }
    }
}

extern "C" void kernel_launch(void* const* d_in, const int* in_sizes, int n_in,
                              void* d_out, int out_size, void* d_ws, size_t ws_size,
                              hipStream_t stream) {
    const float* q = (const float*)d_in[0];
    const float* k = (const float*)d_in[1];
    const float* v = (const float*)d_in[2];
    float* out = (float*)d_out;

    float* Spart = (float*)d_ws;                           // BH*NC*64*64 floats = 8 MB
    float* zpart = Spart + (size_t)BH * NC * E * D;        // BH*NC*64 floats = 128 KB

    k_chunk_sums<<<BH * NC, 256, 0, stream>>>(k, v, Spart, zpart);
    k_scan<<<BH * 17, 256, 0, stream>>>(Spart, zpart);
    k_output<<<BH * NC, 256, 0, stream>>>(q, k, v, Spart, zpart, out);
}

// Round 2
// 68.878 us; speedup vs baseline: 1.4620x; 1.4620x over previous
//
#include <hip/hip_runtime.h>
#include <math.h>

#define B 2
#define T 4096
#define H 8
#define E 64
#define D 64
#define C 128          // chunk length
#define NC (T / C)     // 32 chunks
#define BH (B * H)     // 16
#define EPS 1e-6f
#define PE 68          // padded stride for [*][E] rows (68%4==0 for float4)
#define PC 132         // padded stride for [*][C] rows

__device__ __forceinline__ float phi(float x) {
    // elu(x) + 1
    return x > 0.0f ? x + 1.0f : __expf(x);
}

// ---------------- Kernel 1: per-chunk partial sums ----------------
__global__ __launch_bounds__(256) void k_chunk_sums(
        const float* __restrict__ Kg, const float* __restrict__ Vg,
        float* __restrict__ Spart, float* __restrict__ zpart) {
    int blk = blockIdx.x;           // bh * NC + c
    int bh = blk / NC, c = blk % NC;
    int b = bh / H, h = bh % H;
    int t0 = c * C;
    __shared__ float sK[C][PE];
    __shared__ float sV[C][PE];
    int tid = threadIdx.x;
    const float4* Kg4 = (const float4*)Kg;
    const float4* Vg4 = (const float4*)Vg;

    for (int l = tid; l < C * E / 4; l += 256) {
        int i = l >> 4, e4 = l & 15;
        size_t g = ((size_t)(b * T + t0 + i) * H + h) * (E / 4) + e4;
        float4 kv = Kg4[g];
        *(float4*)&sK[i][e4 * 4] = make_float4(phi(kv.x), phi(kv.y), phi(kv.z), phi(kv.w));
        *(float4*)&sV[i][e4 * 4] = Vg4[g];
    }
    __syncthreads();

    int ty = tid >> 4, tx = tid & 15;
    int e0 = ty * 4, d0 = tx * 4;
    float acc[4][4] = {};
    for (int t = 0; t < C; ++t) {
        float4 a4 = *(const float4*)&sK[t][e0];
        float4 v4 = *(const float4*)&sV[t][d0];
        float a[4] = {a4.x, a4.y, a4.z, a4.w};
        float v[4] = {v4.x, v4.y, v4.z, v4.w};
        #pragma unroll
        for (int u = 0; u < 4; ++u)
            #pragma unroll
            for (int w = 0; w < 4; ++w)
                acc[u][w] += a[u] * v[w];
    }
    float* Sp = Spart + (size_t)blk * (E * D);
    #pragma unroll
    for (int u = 0; u < 4; ++u)
        *(float4*)&Sp[(e0 + u) * D + d0] =
            make_float4(acc[u][0], acc[u][1], acc[u][2], acc[u][3]);

    if (tid < E) {
        float s = 0.0f;
        for (int t = 0; t < C; ++t) s += sK[t][tid];
        zpart[(size_t)blk * E + tid] = s;
    }
}

// ---------------- Kernel 2: exclusive prefix scan over chunks ----------------
__global__ __launch_bounds__(256) void k_scan(
        float* __restrict__ Spart, float* __restrict__ zpart) {
    int bh  = blockIdx.x / 17;
    int sub = blockIdx.x % 17;
    int tid = threadIdx.x;
    if (sub < 16) {
        int l = sub * 256 + tid;
        float run = 0.0f;
        float* base = Spart + (size_t)bh * NC * (E * D) + l;
        for (int c = 0; c < NC; ++c) {
            float t = base[(size_t)c * (E * D)];
            base[(size_t)c * (E * D)] = run;
            run += t;
        }
    } else if (tid < E) {
        float run = 0.0f;
        float* base = zpart + (size_t)bh * NC * E + tid;
        for (int c = 0; c < NC; ++c) {
            float t = base[(size_t)c * E];
            base[(size_t)c * E] = run;
            run += t;
        }
    }
}

// ---------------- Kernel 3: per-chunk output (1024 threads) ----------------
// out_i = phiQ_i @ S0 + sum_{j<=i} (phiQ_i . phiK_j) * V_j
// den_i = phiQ_i . z0 + sum_{j<=i} (phiQ_i . phiK_j)
__global__ __launch_bounds__(1024) void k_output(
        const float* __restrict__ Qg, const float* __restrict__ Kg,
        const float* __restrict__ Vg, const float* __restrict__ Spart,
        const float* __restrict__ zpart, float* __restrict__ Og) {
    int blk = blockIdx.x;
    int bh = blk / NC, c = blk % NC;
    int b = bh / H, h = bh % H;
    int t0 = c * C;

    __shared__ float sQ[C][PE];     // phi(Q), row-major           34816 B
    __shared__ float sA[C * PC];    // scores (lower tri valid)    67584 B
    __shared__ float sS0[E][PE];    // prefix state                17408 B
    __shared__ float sU[C * PE];    // union: K^T [E][PC] -> V [C][PE]  34816 B
    __shared__ float sDen[C];       //                              512 B

    int tid = threadIdx.x;
    const float4* Qg4 = (const float4*)Qg;
    const float4* Kg4 = (const float4*)Kg;
    const float4* Vg4 = (const float4*)Vg;

    // ---- load phi(Q) row-major and phi(K) transposed ----
    for (int l = tid; l < C * E / 4; l += 1024) {   // 2 iters
        int i = l >> 4, e4 = l & 15;
        size_t g = ((size_t)(b * T + t0 + i) * H + h) * (E / 4) + e4;
        float4 qv = Qg4[g];
        *(float4*)&sQ[i][e4 * 4] = make_float4(phi(qv.x), phi(qv.y), phi(qv.z), phi(qv.w));
        float4 kv = Kg4[g];
        float pk[4] = {phi(kv.x), phi(kv.y), phi(kv.z), phi(kv.w)};
        #pragma unroll
        for (int cc = 0; cc < 4; ++cc)
            sU[(e4 * 4 + cc) * PC + i] = pk[cc];    // K^T: [e][i]
    }
    const float4* Sp4 = (const float4*)(Spart + (size_t)blk * (E * D));
    for (int l = tid; l < E * D / 4; l += 1024) {   // 1 iter
        int r = l >> 4, e4 = l & 15;
        *(float4*)&sS0[r][e4 * 4] = Sp4[l];
    }
    __syncthreads();

    // ---- scores: 32x32 grid of 4x4 tiles, wave-balanced row remap ----
    {
        int wv  = tid >> 6;             // 0..15
        int hlf = (tid >> 5) & 1;
        int txs = tid & 31;
        int tys = hlf ? (31 - wv) : wv; // each wave: one low + one high row group
        if (txs <= tys) {
            int i0s = tys * 4, j0s = txs * 4;
            float acc[4][4] = {};
            for (int e = 0; e < E; e += 4) {
                float4 qa[4];
                #pragma unroll
                for (int u = 0; u < 4; ++u)
                    qa[u] = *(const float4*)&sQ[i0s + u][e];
                #pragma unroll
                for (int cc = 0; cc < 4; ++cc) {
                    float4 kb = *(const float4*)&sU[(e + cc) * PC + j0s];
                    #pragma unroll
                    for (int u = 0; u < 4; ++u) {
                        float qv = cc == 0 ? qa[u].x : cc == 1 ? qa[u].y
                                 : cc == 2 ? qa[u].z : qa[u].w;
                        acc[u][0] += qv * kb.x;
                        acc[u][1] += qv * kb.y;
                        acc[u][2] += qv * kb.z;
                        acc[u][3] += qv * kb.w;
                    }
                }
            }
            #pragma unroll
            for (int u = 0; u < 4; ++u)
                *(float4*)&sA[(i0s + u) * PC + j0s] =
                    make_float4(acc[u][0], acc[u][1], acc[u][2], acc[u][3]);
            // upper-triangle entries are never read: no zero-fill needed
        }
    }
    __syncthreads();

    // ---- overwrite K^T with V (row-major) ----
    for (int l = tid; l < C * E / 4; l += 1024) {
        int i = l >> 4, e4 = l & 15;
        size_t g = ((size_t)(b * T + t0 + i) * H + h) * (E / 4) + e4;
        *(float4*)&sU[i * PE + e4 * 4] = Vg4[g];
    }
    // ---- denominators: 8 lanes per row, j <= row only ----
    {
        int row = tid >> 3, l8 = tid & 7;
        const float* zp = zpart + (size_t)blk * E;
        float s = 0.0f;
        for (int e = l8; e < E; e += 8) s += sQ[row][e] * zp[e];
        for (int j = l8; j <= row; j += 8) s += sA[row * PC + j];
        s += __shfl_xor(s, 1);
        s += __shfl_xor(s, 2);
        s += __shfl_xor(s, 4);
        if (l8 == 0) sDen[row] = s;
    }
    __syncthreads();

    // ---- PV + Q@S0: each thread owns rows {ia, 127-ia} x 4 cols (balanced) ----
    {
        int ty2 = tid >> 4, tx2 = tid & 15;
        int ia = ty2, ib = 127 - ty2;   // ia <= 63 < ib
        int d0 = tx2 * 4;
        float acA[4] = {}, acB[4] = {};
        for (int e = 0; e < E; ++e) {
            float4 s0 = *(const float4*)&sS0[e][d0];
            float qa = sQ[ia][e], qb = sQ[ib][e];
            acA[0] += qa * s0.x; acA[1] += qa * s0.y; acA[2] += qa * s0.z; acA[3] += qa * s0.w;
            acB[0] += qb * s0.x; acB[1] += qb * s0.y; acB[2] += qb * s0.z; acB[3] += qb * s0.w;
        }
        for (int j = 0; j <= ia; ++j) {
            float4 v = *(const float4*)&sU[j * PE + d0];
            float aA = sA[ia * PC + j], aB = sA[ib * PC + j];
            acA[0] += aA * v.x; acA[1] += aA * v.y; acA[2] += aA * v.z; acA[3] += aA * v.w;
            acB[0] += aB * v.x; acB[1] += aB * v.y; acB[2] += aB * v.z; acB[3] += aB * v.w;
        }
        for (int j = ia + 1; j <= ib; ++j) {
            float4 v = *(const float4*)&sU[j * PE + d0];
            float aB = sA[ib * PC + j];
            acB[0] += aB * v.x; acB[1] += aB * v.y; acB[2] += aB * v.z; acB[3] += aB * v.w;
        }
        float4* Og4 = (float4*)Og;
        float ziA = 1.0f / (sDen[ia] + EPS);
        float ziB = 1.0f / (sDen[ib] + EPS);
        Og4[((size_t)(b * T + t0 + ia) * H + h) * (E / 4) + tx2] =
            make_float4(acA[0] * ziA, acA[1] * ziA, acA[2] * ziA, acA[3] * ziA);
        Og4[((size_t)(b * T + t0 + ib) * H + h) * (E / 4) + tx2] =
            make_float4(acB[0] * ziB, acB[1] * ziB, acB[2] * ziB, acB[3] * ziB);
    }
}

extern "C" void kernel_launch(void* const* d_in, const int* in_sizes, int n_in,
                              void* d_out, int out_size, void* d_ws, size_t ws_size,
                              hipStream_t stream) {
    const float* q = (const float*)d_in[0];
    const float* k = (const float*)d_in[1];
    const float* v = (const float*)d_in[2];
    float* out = (float*)d_out;

    float* Spart = (float*)d_ws;                           // BH*NC*64*64 floats = 8 MB
    float* zpart = Spart + (size_t)BH * NC * E * D;        // BH*NC*64 floats = 128 KB

    k_chunk_sums<<<BH * NC, 256, 0, stream>>>(k, v, Spart, zpart);
    k_scan<<<BH * 17, 256, 0, stream>>>(Spart, zpart);
    k_output<<<BH * NC, 1024, 0, stream>>>(q, k, v, Spart, zpart, out);
}

// Round 3
// 44.451 us; speedup vs baseline: 2.2654x; 1.5495x over previous
//
#include <hip/hip_runtime.h>
#include <math.h>

#define B 2
#define T 4096
#define H 8
#define E 64
#define D 64
#define C 128          // chunk length
#define NC (T / C)     // 32 chunks
#define BH (B * H)     // 16
#define EPS 1e-6f
#define PE 68          // fp32 LDS pad (kernel 1)
#define PQ 72          // bf16 row stride for sQ/sK (144B -> bank delta 4)
#define PBT 200        // bf16 row stride for sBt (400B -> bank delta 4)

typedef short short8 __attribute__((ext_vector_type(8)));
typedef float f32x4 __attribute__((ext_vector_type(4)));

__device__ __forceinline__ float phi(float x) {
    return x > 0.0f ? x + 1.0f : __expf(x);
}
__device__ __forceinline__ ushort f2bf(float f) {   // RNE float->bf16
    uint u = __float_as_uint(f);
    return (ushort)((u + 0x7FFFu + ((u >> 16) & 1u)) >> 16);
}
__device__ __forceinline__ float bf2f(ushort h) {
    return __uint_as_float(((uint)h) << 16);
}

// ---------------- Kernel 1: per-chunk partial sums (fp32, unchanged) --------
__global__ __launch_bounds__(256) void k_chunk_sums(
        const float* __restrict__ Kg, const float* __restrict__ Vg,
        float* __restrict__ Spart, float* __restrict__ zpart) {
    int blk = blockIdx.x;
    int bh = blk / NC, c = blk % NC;
    int b = bh / H, h = bh % H;
    int t0 = c * C;
    __shared__ float sK[C][PE];
    __shared__ float sV[C][PE];
    int tid = threadIdx.x;
    const float4* Kg4 = (const float4*)Kg;
    const float4* Vg4 = (const float4*)Vg;

    for (int l = tid; l < C * E / 4; l += 256) {
        int i = l >> 4, e4 = l & 15;
        size_t g = ((size_t)(b * T + t0 + i) * H + h) * (E / 4) + e4;
        float4 kv = Kg4[g];
        *(float4*)&sK[i][e4 * 4] = make_float4(phi(kv.x), phi(kv.y), phi(kv.z), phi(kv.w));
        *(float4*)&sV[i][e4 * 4] = Vg4[g];
    }
    __syncthreads();

    int ty = tid >> 4, tx = tid & 15;
    int e0 = ty * 4, d0 = tx * 4;
    float acc[4][4] = {};
    for (int t = 0; t < C; ++t) {
        float4 a4 = *(const float4*)&sK[t][e0];
        float4 v4 = *(const float4*)&sV[t][d0];
        float a[4] = {a4.x, a4.y, a4.z, a4.w};
        float v[4] = {v4.x, v4.y, v4.z, v4.w};
        #pragma unroll
        for (int u = 0; u < 4; ++u)
            #pragma unroll
            for (int w = 0; w < 4; ++w)
                acc[u][w] += a[u] * v[w];
    }
    float* Sp = Spart + (size_t)blk * (E * D);
    #pragma unroll
    for (int u = 0; u < 4; ++u)
        *(float4*)&Sp[(e0 + u) * D + d0] =
            make_float4(acc[u][0], acc[u][1], acc[u][2], acc[u][3]);

    if (tid < E) {
        float s = 0.0f;
        for (int t = 0; t < C; ++t) s += sK[t][tid];
        zpart[(size_t)blk * E + tid] = s;
    }
}

// ---------------- Kernel 2: exclusive prefix scan over chunks (unchanged) ---
__global__ __launch_bounds__(256) void k_scan(
        float* __restrict__ Spart, float* __restrict__ zpart) {
    int bh  = blockIdx.x / 17;
    int sub = blockIdx.x % 17;
    int tid = threadIdx.x;
    if (sub < 16) {
        int l = sub * 256 + tid;
        float run = 0.0f;
        float* base = Spart + (size_t)bh * NC * (E * D) + l;
        for (int c = 0; c < NC; ++c) {
            float t = base[(size_t)c * (E * D)];
            base[(size_t)c * (E * D)] = run;
            run += t;
        }
    } else if (tid < E) {
        float run = 0.0f;
        float* base = zpart + (size_t)bh * NC * E + tid;
        for (int c = 0; c < NC; ++c) {
            float t = base[(size_t)c * E];
            base[(size_t)c * E] = run;
            run += t;
        }
    }
}

// ---------------- Kernel 3: per-chunk output via MFMA (512 threads) ---------
// S = phiQ @ phiK^T (causal-masked, bf16)      128x128, K=64
// O = [S | phiQ] @ [V ; S0]                    128x64,  K=192
// den_i = rowsum(S_i) + phiQ_i . z0 ;  out_i = O_i / (den_i + eps)
__global__ __launch_bounds__(512, 4) void k_output(
        const float* __restrict__ Qg, const float* __restrict__ Kg,
        const float* __restrict__ Vg, const float* __restrict__ Spart,
        const float* __restrict__ zpart, float* __restrict__ Og) {
    int blk = blockIdx.x;
    int bh = blk / NC, c = blk % NC;
    int b = bh / H, h = bh % H;
    int t0 = c * C;

    __shared__ ushort sQ[C][PQ];        // phi(Q) bf16, row-major     18432 B
    __shared__ ushort sKB[64 * PBT];    // phi(K)[C][PQ] -> Bt[64][PBT] 25600 B
    __shared__ ushort sA[C][C];         // masked scores, XOR-swizzled 32768 B
    __shared__ float  sDen[C];
    __shared__ float  sZ[E];

    int tid = threadIdx.x;
    int lane = tid & 63;
    int w = tid >> 6;                   // wave 0..7

    const float4* Qg4 = (const float4*)Qg;
    const float4* Kg4 = (const float4*)Kg;
    const float4* Vg4 = (const float4*)Vg;

    // ---- phase A: load phi(Q), phi(K) -> bf16 LDS; prefetch V,S0 to regs ----
    for (int l = tid; l < C * 8; l += 512) {        // 2 iters
        int i = l >> 3, e8 = l & 7;
        size_t g = ((size_t)(b * T + t0 + i) * H + h) * 16 + e8 * 2;
        float4 qa = Qg4[g], qb = Qg4[g + 1];
        short8 qv;
        qv[0] = (short)f2bf(phi(qa.x)); qv[1] = (short)f2bf(phi(qa.y));
        qv[2] = (short)f2bf(phi(qa.z)); qv[3] = (short)f2bf(phi(qa.w));
        qv[4] = (short)f2bf(phi(qb.x)); qv[5] = (short)f2bf(phi(qb.y));
        qv[6] = (short)f2bf(phi(qb.z)); qv[7] = (short)f2bf(phi(qb.w));
        *(short8*)&sQ[i][e8 * 8] = qv;
        float4 ka = Kg4[g], kb = Kg4[g + 1];
        short8 kv;
        kv[0] = (short)f2bf(phi(ka.x)); kv[1] = (short)f2bf(phi(ka.y));
        kv[2] = (short)f2bf(phi(ka.z)); kv[3] = (short)f2bf(phi(ka.w));
        kv[4] = (short)f2bf(phi(kb.x)); kv[5] = (short)f2bf(phi(kb.y));
        kv[6] = (short)f2bf(phi(kb.z)); kv[7] = (short)f2bf(phi(kb.w));
        *(short8*)&sKB[i * PQ + e8 * 8] = kv;
    }
    // pre-zero score buffer (upper triangle must read as 0 in PV)
    {
        short8 zz = {0, 0, 0, 0, 0, 0, 0, 0};
        ushort* af = (ushort*)sA;
        #pragma unroll
        for (int it = 0; it < 4; ++it)
            *(short8*)&af[(tid + 512 * it) * 8] = zz;
    }
    int cg = tid & 15, rr = tid >> 4;   // col-group, row within group
    float4 vreg[4];
    #pragma unroll
    for (int it = 0; it < 4; ++it) {
        int j = rr + 32 * it;
        vreg[it] = Vg4[((size_t)(b * T + t0 + j) * H + h) * 16 + cg];
    }
    const float4* Sp4 = (const float4*)(Spart + (size_t)blk * (E * D));
    float4 sreg[2];
    #pragma unroll
    for (int it = 0; it < 2; ++it)
        sreg[it] = Sp4[(rr + 32 * it) * 16 + cg];
    if (tid < E) sZ[tid] = zpart[(size_t)blk * E + tid];
    __syncthreads();

    // ---- phase B: scores via MFMA, lower-triangle tiles only ----
    for (int idx = w; idx < 36; idx += 8) {
        int tr = 0;
        while ((tr + 1) * (tr + 2) / 2 <= idx) ++tr;
        int tc = idx - tr * (tr + 1) / 2;
        int am = tr * 16 + (lane & 15);
        int bn = tc * 16 + (lane & 15);
        int kb = (lane >> 4) * 8;
        f32x4 acc = {};
        #pragma unroll
        for (int ks = 0; ks < 2; ++ks) {
            short8 a  = *(const short8*)&sQ[am][ks * 32 + kb];
            short8 bb = *(const short8*)&sKB[bn * PQ + ks * 32 + kb];
            acc = __builtin_amdgcn_mfma_f32_16x16x32_bf16(a, bb, acc, 0, 0, 0);
        }
        int colb = tc * 16 + (lane & 15);
        #pragma unroll
        for (int r = 0; r < 4; ++r) {
            int row = tr * 16 + (lane >> 4) * 4 + r;
            if (tr == tc && colb > row) continue;   // stays pre-zeroed
            sA[row][colb ^ ((row & 7) << 3)] = f2bf(acc[r]);
        }
    }
    __syncthreads();

    // ---- phase C: build Bt = [V ; S0]^T (bf16) in sKB (K is dead now) ----
    #pragma unroll
    for (int it = 0; it < 4; ++it) {
        int j = rr + 32 * it;
        float4 v = vreg[it];
        int d0 = cg * 4;
        sKB[(d0 + 0) * PBT + j] = f2bf(v.x);
        sKB[(d0 + 1) * PBT + j] = f2bf(v.y);
        sKB[(d0 + 2) * PBT + j] = f2bf(v.z);
        sKB[(d0 + 3) * PBT + j] = f2bf(v.w);
    }
    #pragma unroll
    for (int it = 0; it < 2; ++it) {
        int e = rr + 32 * it;
        float4 s = sreg[it];
        int d0 = cg * 4;
        sKB[(d0 + 0) * PBT + 128 + e] = f2bf(s.x);
        sKB[(d0 + 1) * PBT + 128 + e] = f2bf(s.y);
        sKB[(d0 + 2) * PBT + 128 + e] = f2bf(s.z);
        sKB[(d0 + 3) * PBT + 128 + e] = f2bf(s.w);
    }
    // denominators: 2 threads per row (swizzle-invariant half-row sums)
    if (tid < 256) {
        int row = tid >> 1, hf = tid & 1;
        float s = 0.0f;
        const ushort* ar = &sA[row][hf * 64];
        #pragma unroll
        for (int q8 = 0; q8 < 8; ++q8) {
            int cq = (q8 + row) & 7;            // rotate to spread banks
            short8 v = *(const short8*)&ar[cq * 8];
            #pragma unroll
            for (int j = 0; j < 8; ++j) s += bf2f((ushort)v[j]);
        }
        const ushort* qr = &sQ[row][0];
        #pragma unroll
        for (int e = 0; e < 32; ++e) {
            int ee = hf * 32 + e;
            s += bf2f(qr[ee]) * sZ[ee];
        }
        s += __shfl_xor(s, 1);
        if (hf == 0) sDen[row] = s;
    }
    __syncthreads();

    // ---- phase D: O = [S | phiQ] @ Bt^T via MFMA, scale, store ----
    {
        int tcn = w & 3;                 // output col tile (n0 = tcn*16)
        int trb = w >> 2;                // 0 or 1
        int ncol = tcn * 16 + (lane & 15);
        int g8 = (lane >> 4) * 8;
        #pragma unroll
        for (int rt = 0; rt < 4; ++rt) {
            int tr = trb + rt * 2;
            int m0 = tr * 16;
            int arow = m0 + (lane & 15);
            int aswz = arow & 7;
            f32x4 acc = {};
            int smax = (m0 + 15) >> 5;   // skip all-zero causal K-steps
            for (int s = 0; s <= smax; ++s) {
                int chunk = s * 4 + (lane >> 4);
                short8 a  = *(const short8*)&sA[arow][(chunk ^ aswz) * 8];
                short8 bb = *(const short8*)&sKB[ncol * PBT + s * 32 + g8];
                acc = __builtin_amdgcn_mfma_f32_16x16x32_bf16(a, bb, acc, 0, 0, 0);
            }
            #pragma unroll
            for (int s = 0; s < 2; ++s) {    // Q @ S0 tail (K = 128..191)
                short8 a  = *(const short8*)&sQ[arow][s * 32 + g8];
                short8 bb = *(const short8*)&sKB[ncol * PBT + 128 + s * 32 + g8];
                acc = __builtin_amdgcn_mfma_f32_16x16x32_bf16(a, bb, acc, 0, 0, 0);
            }
            #pragma unroll
            for (int r = 0; r < 4; ++r) {
                int row = m0 + (lane >> 4) * 4 + r;
                float z = 1.0f / (sDen[row] + EPS);
                Og[((size_t)(b * T + t0 + row) * H + h) * 64 + ncol] = acc[r] * z;
            }
        }
    }
}

extern "C" void kernel_launch(void* const* d_in, const int* in_sizes, int n_in,
                              void* d_out, int out_size, void* d_ws, size_t ws_size,
                              hipStream_t stream) {
    const float* q = (const float*)d_in[0];
    const float* k = (const float*)d_in[1];
    const float* v = (const float*)d_in[2];
    float* out = (float*)d_out;

    float* Spart = (float*)d_ws;                           // 8 MB
    float* zpart = Spart + (size_t)BH * NC * E * D;        // 128 KB

    k_chunk_sums<<<BH * NC, 256, 0, stream>>>(k, v, Spart, zpart);
    k_scan<<<BH * 17, 256, 0, stream>>>(Spart, zpart);
    k_output<<<BH * NC, 512, 0, stream>>>(q, k, v, Spart, zpart, out);
}

// Round 4
// 35.221 us; speedup vs baseline: 2.8591x; 1.2620x over previous
//
#include <hip/hip_runtime.h>
#include <math.h>

#define B 2
#define T 4096
#define H 8
#define E 64
#define D 64
#define C 128          // chunk length
#define NC (T / C)     // 32 chunks
#define BH (B * H)     // 16
#define EPS 1e-6f
#define PT 132         // bf16 row stride for transposed [64][t] tiles (k1)
#define PQ 72          // bf16 row stride for sQ/sK
#define PBT 200        // bf16 row stride for sBt
typedef short short8 __attribute__((ext_vector_type(8)));
typedef short short4v __attribute__((ext_vector_type(4)));
typedef float f32x4 __attribute__((ext_vector_type(4)));

__device__ __forceinline__ float phi(float x) {
    return x > 0.0f ? x + 1.0f : __expf(x);
}
__device__ __forceinline__ ushort f2bf(float f) {   // RNE float->bf16
    uint u = __float_as_uint(f);
    return (ushort)((u + 0x7FFFu + ((u >> 16) & 1u)) >> 16);
}
__device__ __forceinline__ float bf2f(ushort h) {
    return __uint_as_float(((uint)h) << 16);
}

// ---------------- Kernel 1: per-chunk partial sums via MFMA ----------------
// SpartT[blk][d][e] = sum_t V[t][d] * phiK[t][e]   (fp32 out, bf16 inputs)
// VTg[blk][d][t]    = bf16 V^T  (pre-staged for k_output's Bt)
// zpart[blk][e]     = sum_t phiK[t][e]
__global__ __launch_bounds__(256) void k_chunk_sums(
        const float* __restrict__ Kg, const float* __restrict__ Vg,
        float* __restrict__ SpartT, float* __restrict__ zpart,
        ushort* __restrict__ VTg) {
    int blk = blockIdx.x;
    int bh = blk / NC, c = blk % NC;
    int b = bh / H, h = bh % H;
    int t0 = c * C;
    __shared__ ushort sKt[E][PT];   // phiK^T [e][t]
    __shared__ ushort sVt[D][PT];   // V^T    [d][t]
    int tid = threadIdx.x;
    int lane = tid & 63, w = tid >> 6;
    const float4* Kg4 = (const float4*)Kg;
    const float4* Vg4 = (const float4*)Vg;

    for (int l = tid; l < C * E / 4; l += 256) {    // 8 iters
        int i = l >> 4, e4 = l & 15;
        size_t g = ((size_t)(b * T + t0 + i) * H + h) * 16 + e4;
        float4 kv = Kg4[g];
        float pk[4] = {phi(kv.x), phi(kv.y), phi(kv.z), phi(kv.w)};
        float4 vv = Vg4[g];
        float pv[4] = {vv.x, vv.y, vv.z, vv.w};
        #pragma unroll
        for (int cc = 0; cc < 4; ++cc) {
            sKt[e4 * 4 + cc][i] = f2bf(pk[cc]);
            sVt[e4 * 4 + cc][i] = f2bf(pv[cc]);
        }
    }
    __syncthreads();

    // S^T = V^T @ phiK : 16 tiles of 16x16, K=128 (4 k-steps), 4 waves
    float* Sp = SpartT + (size_t)blk * (E * D);
    #pragma unroll
    for (int tt = 0; tt < 4; ++tt) {
        int idx = w * 4 + tt;
        int mt = idx >> 2, nt = idx & 3;
        int am = mt * 16 + (lane & 15);
        int bn = nt * 16 + (lane & 15);
        int kb = (lane >> 4) * 8;
        f32x4 acc = {};
        #pragma unroll
        for (int ks = 0; ks < 4; ++ks) {
            short8 a  = *(const short8*)&sVt[am][ks * 32 + kb];
            short8 bb = *(const short8*)&sKt[bn][ks * 32 + kb];
            acc = __builtin_amdgcn_mfma_f32_16x16x32_bf16(a, bb, acc, 0, 0, 0);
        }
        #pragma unroll
        for (int r = 0; r < 4; ++r) {
            int drow = mt * 16 + (lane >> 4) * 4 + r;
            Sp[drow * E + bn] = acc[r];
        }
    }
    // stage V^T bf16 to global (coalesced short8 rows)
    ushort* vt = VTg + (size_t)blk * (C * D);
    for (int l = tid; l < C * D / 8; l += 256) {    // 4 iters
        int d = l >> 4, p = l & 15;
        *(short8*)&vt[d * C + p * 8] = *(const short8*)&sVt[d][p * 8];
    }
    if (tid < E) {
        float s = 0.0f;
        #pragma unroll
        for (int p = 0; p < 16; ++p) {
            short8 v = *(const short8*)&sKt[tid][p * 8];
            #pragma unroll
            for (int j = 0; j < 8; ++j) s += bf2f((ushort)v[j]);
        }
        zpart[(size_t)blk * E + tid] = s;
    }
}

// ---------------- Kernel 2: exclusive prefix scan (register-pipelined) ------
__global__ __launch_bounds__(256) void k_scan(
        float* __restrict__ SpartT, float* __restrict__ zpart) {
    int bh  = blockIdx.x / 17;
    int sub = blockIdx.x % 17;
    int tid = threadIdx.x;
    if (sub < 16) {
        int l = sub * 256 + tid;
        float* base = SpartT + (size_t)bh * NC * (E * D) + l;
        float vals[NC];
        #pragma unroll
        for (int c = 0; c < NC; ++c) vals[c] = base[(size_t)c * (E * D)];
        float run = 0.0f;
        #pragma unroll
        for (int c = 0; c < NC; ++c) {
            base[(size_t)c * (E * D)] = run;
            run += vals[c];
        }
    } else if (tid < E) {
        float* base = zpart + (size_t)bh * NC * E + tid;
        float vals[NC];
        #pragma unroll
        for (int c = 0; c < NC; ++c) vals[c] = base[(size_t)c * E];
        float run = 0.0f;
        #pragma unroll
        for (int c = 0; c < NC; ++c) {
            base[(size_t)c * E] = run;
            run += vals[c];
        }
    }
}

// ---------------- Kernel 3: per-chunk output via MFMA (512 threads) ---------
// S = phiQ @ phiK^T (causal-masked, bf16)      128x128, K=64
// O = [S | phiQ] @ [V ; S0]                    128x64,  K=192
// den_i = rowsum(S_i) + phiQ_i . z0 ;  out_i = O_i / (den_i + eps)
__global__ __launch_bounds__(512, 4) void k_output(
        const float* __restrict__ Qg, const float* __restrict__ Kg,
        const ushort* __restrict__ VTg, const float* __restrict__ SpartT,
        const float* __restrict__ zpart, float* __restrict__ Og) {
    int blk = blockIdx.x;
    int bh = blk / NC, c = blk % NC;
    int b = bh / H, h = bh % H;
    int t0 = c * C;

    __shared__ ushort sQ[C][PQ];        // phi(Q) bf16, row-major     18432 B
    __shared__ ushort sKB[64 * PBT];    // phi(K)[C][PQ] -> Bt[64][PBT] 25600 B
    __shared__ ushort sA[C][C];         // masked scores, XOR-swizzled 32768 B
    __shared__ float  sDen[C];
    __shared__ float  sZ[E];

    int tid = threadIdx.x;
    int lane = tid & 63;
    int w = tid >> 6;                   // wave 0..7

    const float4* Qg4 = (const float4*)Qg;
    const float4* Kg4 = (const float4*)Kg;

    // ---- phase A: load phi(Q), phi(K) -> bf16 LDS; prefetch V^T,S0 to regs --
    for (int l = tid; l < C * 8; l += 512) {        // 2 iters
        int i = l >> 3, e8 = l & 7;
        size_t g = ((size_t)(b * T + t0 + i) * H + h) * 16 + e8 * 2;
        float4 qa = Qg4[g], qb = Qg4[g + 1];
        short8 qv;
        qv[0] = (short)f2bf(phi(qa.x)); qv[1] = (short)f2bf(phi(qa.y));
        qv[2] = (short)f2bf(phi(qa.z)); qv[3] = (short)f2bf(phi(qa.w));
        qv[4] = (short)f2bf(phi(qb.x)); qv[5] = (short)f2bf(phi(qb.y));
        qv[6] = (short)f2bf(phi(qb.z)); qv[7] = (short)f2bf(phi(qb.w));
        *(short8*)&sQ[i][e8 * 8] = qv;
        float4 ka = Kg4[g], kb = Kg4[g + 1];
        short8 kv;
        kv[0] = (short)f2bf(phi(ka.x)); kv[1] = (short)f2bf(phi(ka.y));
        kv[2] = (short)f2bf(phi(ka.z)); kv[3] = (short)f2bf(phi(ka.w));
        kv[4] = (short)f2bf(phi(kb.x)); kv[5] = (short)f2bf(phi(kb.y));
        kv[6] = (short)f2bf(phi(kb.z)); kv[7] = (short)f2bf(phi(kb.w));
        *(short8*)&sKB[i * PQ + e8 * 8] = kv;
    }
    // pre-zero score buffer (upper triangle must read as 0 in PV)
    {
        short8 zz = {0, 0, 0, 0, 0, 0, 0, 0};
        ushort* af = (ushort*)sA;
        #pragma unroll
        for (int it = 0; it < 4; ++it)
            *(short8*)&af[(tid + 512 * it) * 8] = zz;
    }
    // V^T bf16 (2 x short8) and S0T fp32 (2 x float4) straight to regs
    const short8* vt8 = (const short8*)(VTg + (size_t)blk * (C * D));
    short8 vtreg[2];
    #pragma unroll
    for (int it = 0; it < 2; ++it) vtreg[it] = vt8[tid * 2 + it];
    const float4* Sp4 = (const float4*)(SpartT + (size_t)blk * (E * D));
    float4 s0reg[2];
    #pragma unroll
    for (int it = 0; it < 2; ++it) s0reg[it] = Sp4[tid * 2 + it];
    if (tid < E) sZ[tid] = zpart[(size_t)blk * E + tid];
    __syncthreads();

    // ---- phase B: scores via MFMA, lower-triangle tiles only ----
    for (int idx = w; idx < 36; idx += 8) {
        int tr = 0;
        while ((tr + 1) * (tr + 2) / 2 <= idx) ++tr;
        int tc = idx - tr * (tr + 1) / 2;
        int am = tr * 16 + (lane & 15);
        int bn = tc * 16 + (lane & 15);
        int kb = (lane >> 4) * 8;
        f32x4 acc = {};
        #pragma unroll
        for (int ks = 0; ks < 2; ++ks) {
            short8 a  = *(const short8*)&sQ[am][ks * 32 + kb];
            short8 bb = *(const short8*)&sKB[bn * PQ + ks * 32 + kb];
            acc = __builtin_amdgcn_mfma_f32_16x16x32_bf16(a, bb, acc, 0, 0, 0);
        }
        int colb = tc * 16 + (lane & 15);
        #pragma unroll
        for (int r = 0; r < 4; ++r) {
            int row = tr * 16 + (lane >> 4) * 4 + r;
            if (tr == tc && colb > row) continue;   // stays pre-zeroed
            sA[row][colb ^ ((row & 7) << 3)] = f2bf(acc[r]);
        }
    }
    __syncthreads();

    // ---- phase C: build Bt = [V ; S0]^T in sKB (K is dead) — vectorized ----
    #pragma unroll
    for (int it = 0; it < 2; ++it) {
        int idx = tid * 2 + it;         // short8 index over [64][16]
        int d = idx >> 4, p = idx & 15;
        *(short8*)&sKB[d * PBT + p * 8] = vtreg[it];
    }
    #pragma unroll
    for (int it = 0; it < 2; ++it) {
        int idx = tid * 2 + it;         // float4 index over [64][16]
        int d = idx >> 4, e0 = (idx & 15) * 4;
        float4 s = s0reg[it];
        short4v sv;
        sv[0] = (short)f2bf(s.x); sv[1] = (short)f2bf(s.y);
        sv[2] = (short)f2bf(s.z); sv[3] = (short)f2bf(s.w);
        *(short4v*)&sKB[d * PBT + 128 + e0] = sv;
    }
    // denominators: 2 threads per row (swizzle-invariant half-row sums)
    if (tid < 256) {
        int row = tid >> 1, hf = tid & 1;
        float s = 0.0f;
        const ushort* ar = &sA[row][hf * 64];
        #pragma unroll
        for (int q8 = 0; q8 < 8; ++q8) {
            int cq = (q8 + row) & 7;            // rotate to spread banks
            short8 v = *(const short8*)&ar[cq * 8];
            #pragma unroll
            for (int j = 0; j < 8; ++j) s += bf2f((ushort)v[j]);
        }
        const ushort* qr = &sQ[row][0];
        #pragma unroll
        for (int e = 0; e < 32; ++e) {
            int ee = hf * 32 + e;
            s += bf2f(qr[ee]) * sZ[ee];
        }
        s += __shfl_xor(s, 1);
        if (hf == 0) sDen[row] = s;
    }
    __syncthreads();

    // ---- phase D: O = [S | phiQ] @ Bt^T via MFMA, scale, store ----
    {
        int tcn = w & 3;                 // output col tile (n0 = tcn*16)
        int trb = w >> 2;                // 0 or 1
        int ncol = tcn * 16 + (lane & 15);
        int g8 = (lane >> 4) * 8;
        #pragma unroll
        for (int rt = 0; rt < 4; ++rt) {
            int tr = trb + rt * 2;
            int m0 = tr * 16;
            int arow = m0 + (lane & 15);
            int aswz = arow & 7;
            f32x4 acc = {};
            int smax = (m0 + 15) >> 5;   // skip all-zero causal K-steps
            for (int s = 0; s <= smax; ++s) {
                int chunk = s * 4 + (lane >> 4);
                short8 a  = *(const short8*)&sA[arow][(chunk ^ aswz) * 8];
                short8 bb = *(const short8*)&sKB[ncol * PBT + s * 32 + g8];
                acc = __builtin_amdgcn_mfma_f32_16x16x32_bf16(a, bb, acc, 0, 0, 0);
            }
            #pragma unroll
            for (int s = 0; s < 2; ++s) {    // Q @ S0 tail (K = 128..191)
                short8 a  = *(const short8*)&sQ[arow][s * 32 + g8];
                short8 bb = *(const short8*)&sKB[ncol * PBT + 128 + s * 32 + g8];
                acc = __builtin_amdgcn_mfma_f32_16x16x32_bf16(a, bb, acc, 0, 0, 0);
            }
            #pragma unroll
            for (int r = 0; r < 4; ++r) {
                int row = m0 + (lane >> 4) * 4 + r;
                float z = 1.0f / (sDen[row] + EPS);
                Og[((size_t)(b * T + t0 + row) * H + h) * 64 + ncol] = acc[r] * z;
            }
        }
    }
}

extern "C" void kernel_launch(void* const* d_in, const int* in_sizes, int n_in,
                              void* d_out, int out_size, void* d_ws, size_t ws_size,
                              hipStream_t stream) {
    const float* q = (const float*)d_in[0];
    const float* k = (const float*)d_in[1];
    const float* v = (const float*)d_in[2];
    float* out = (float*)d_out;

    float*  SpartT = (float*)d_ws;                            // 8 MB
    float*  zpart  = SpartT + (size_t)BH * NC * E * D;        // 128 KB
    ushort* VTg    = (ushort*)(zpart + (size_t)BH * NC * E);  // 8 MB bf16

    k_chunk_sums<<<BH * NC, 256, 0, stream>>>(k, v, SpartT, zpart, VTg);
    k_scan<<<BH * 17, 256, 0, stream>>>(SpartT, zpart);
    k_output<<<BH * NC, 512, 0, stream>>>(q, k, VTg, SpartT, zpart, out);
}

// Round 5
// 32.763 us; speedup vs baseline: 3.0736x; 1.0750x over previous
//
#include <hip/hip_runtime.h>
#include <hip/hip_bf16.h>
#include <math.h>

#define B 2
#define T 4096
#define H 8
#define E 64
#define D 64
#define C 128          // chunk length
#define NC (T / C)     // 32 chunks
#define BH (B * H)     // 16
#define EPS 1e-6f
#define PT 132         // bf16 row stride for k1 transposed tiles
#define PQ 72          // bf16 row stride sQ / phiK in sKB (144B, 16B-aligned)
#define PBT 200        // bf16 row stride Bt (400B, 16B-aligned)

typedef short short8 __attribute__((ext_vector_type(8)));
typedef float f32x4 __attribute__((ext_vector_type(4)));

__device__ __forceinline__ float phi(float x) {
    return x > 0.0f ? x + 1.0f : __expf(x);
}
__device__ __forceinline__ uint pk2(float a, float b) {   // 2xf32 -> packed bf16 (RNE)
    __hip_bfloat162 h = __float22bfloat162_rn(make_float2(a, b));
    union { __hip_bfloat162 h2; uint u; } cv; cv.h2 = h; return cv.u;
}
__device__ __forceinline__ ushort f2bf(float f) {
    uint u = __float_as_uint(f);
    return (ushort)((u + 0x7FFFu + ((u >> 16) & 1u)) >> 16);
}

// ---------------- Kernel 1: per-chunk partials via MFMA ----------------
// SpartT[blk][d][e] = sum_t phiK[t][e] * V[t][d]   (fp32)
// VTg[blk][d][t]  bf16 V^T ;  PKg[blk][t][e] bf16 phiK ;  zpart[blk][e] colsum
__global__ __launch_bounds__(256) void k_chunk_sums(
        const float* __restrict__ Kg, const float* __restrict__ Vg,
        float* __restrict__ SpartT, float* __restrict__ zpart,
        ushort* __restrict__ VTg, ushort* __restrict__ PKg) {
    int blk = blockIdx.x;
    int bh = blk / NC, c = blk % NC;
    int b = bh / H, h = bh % H;
    int t0 = c * C;
    __shared__ ushort sKt[E][PT];   // phiK^T [e][t]
    __shared__ ushort sVt[D][PT];   // V^T    [d][t]
    int tid = threadIdx.x;
    int lane = tid & 63, w = tid >> 6;
    const float4* Kg4 = (const float4*)Kg;
    const float4* Vg4 = (const float4*)Vg;
    uint2* PK2 = (uint2*)(PKg + (size_t)blk * (C * E));

    for (int l = tid; l < (C / 2) * 16; l += 256) {   // 4 iters
        int i2 = l >> 4, e4 = l & 15;
        int t = i2 * 2;
        size_t g0 = ((size_t)(b * T + t0 + t) * H + h) * 16 + e4;
        size_t g1 = g0 + H * 16;                      // next t row
        float4 ka = Kg4[g0], kb = Kg4[g1];
        float4 va = Vg4[g0], vb = Vg4[g1];
        float pk0[4] = {phi(ka.x), phi(ka.y), phi(ka.z), phi(ka.w)};
        float pk1[4] = {phi(kb.x), phi(kb.y), phi(kb.z), phi(kb.w)};
        float pv0[4] = {va.x, va.y, va.z, va.w};
        float pv1[4] = {vb.x, vb.y, vb.z, vb.w};
        #pragma unroll
        for (int cc = 0; cc < 4; ++cc) {              // t-paired uint stores
            *(uint*)&sKt[e4 * 4 + cc][t] = pk2(pk0[cc], pk1[cc]);
            *(uint*)&sVt[e4 * 4 + cc][t] = pk2(pv0[cc], pv1[cc]);
        }
        PK2[t * 16 + e4]       = make_uint2(pk2(pk0[0], pk0[1]), pk2(pk0[2], pk0[3]));
        PK2[(t + 1) * 16 + e4] = make_uint2(pk2(pk1[0], pk1[1]), pk2(pk1[2], pk1[3]));
    }
    __syncthreads();

    // S^T: D[m=e][n=d] = sum_t phiK^T[e][t] V^T[d][t]; wave w owns e-tile w
    {
        int g = lane >> 4, cl = lane & 15;
        int mt = w;
        f32x4 acc[4] = {};
        for (int ks = 0; ks < 4; ++ks) {
            short8 a = *(const short8*)&sKt[mt * 16 + cl][ks * 32 + g * 8];
            #pragma unroll
            for (int nt = 0; nt < 4; ++nt) {
                short8 bb = *(const short8*)&sVt[nt * 16 + cl][ks * 32 + g * 8];
                acc[nt] = __builtin_amdgcn_mfma_f32_16x16x32_bf16(a, bb, acc[nt], 0, 0, 0);
            }
        }
        float* Sp = SpartT + (size_t)blk * (E * D);
        #pragma unroll
        for (int nt = 0; nt < 4; ++nt) {
            int d = nt * 16 + cl;
            *(float4*)&Sp[d * E + mt * 16 + g * 4] =
                make_float4(acc[nt][0], acc[nt][1], acc[nt][2], acc[nt][3]);
        }
    }
    // stage V^T bf16 to global
    ushort* vt = VTg + (size_t)blk * (C * D);
    for (int l = tid; l < C * D / 8; l += 256)
        *(short8*)&vt[(l >> 4) * C + (l & 15) * 8] = *(const short8*)&sVt[l >> 4][(l & 15) * 8];
    if (tid < E) {
        float s = 0.0f;
        #pragma unroll
        for (int p = 0; p < 16; ++p) {
            short8 v = *(const short8*)&sKt[tid][p * 8];
            #pragma unroll
            for (int j = 0; j < 8; ++j) s += __uint_as_float(((uint)(ushort)v[j]) << 16);
        }
        zpart[(size_t)blk * E + tid] = s;
    }
}

// ---------------- Kernel 2: exclusive prefix scan; S0 emitted bf16 ----------
__global__ __launch_bounds__(256) void k_scan(
        const float* __restrict__ SpartT, float* __restrict__ zpart,
        ushort* __restrict__ S0bf) {
    int bh  = blockIdx.x / 17;
    int sub = blockIdx.x % 17;
    int tid = threadIdx.x;
    if (sub < 16) {
        int l = sub * 256 + tid;
        const float* base = SpartT + (size_t)bh * NC * (E * D) + l;
        ushort* obase = S0bf + (size_t)bh * NC * (E * D) + l;
        float vals[NC];
        #pragma unroll
        for (int c = 0; c < NC; ++c) vals[c] = base[(size_t)c * (E * D)];
        float run = 0.0f;
        #pragma unroll
        for (int c = 0; c < NC; ++c) {
            obase[(size_t)c * (E * D)] = f2bf(run);
            run += vals[c];
        }
    } else if (tid < E) {
        float* base = zpart + (size_t)bh * NC * E + tid;
        float vals[NC];
        #pragma unroll
        for (int c = 0; c < NC; ++c) vals[c] = base[(size_t)c * E];
        float run = 0.0f;
        #pragma unroll
        for (int c = 0; c < NC; ++c) {
            base[(size_t)c * E] = run;
            run += vals[c];
        }
    }
}

// ---------------- Kernel 3: per-chunk output via MFMA (512 threads) ---------
// S = phiQ @ phiK^T (causal, bf16, XOR-swizzled)
// [O | den] = [S | phiQ] @ [V ; S0 | ones ; z]   (den from 5th n-tile)
__global__ __launch_bounds__(512, 4) void k_output(
        const float* __restrict__ Qg, const ushort* __restrict__ PKg,
        const ushort* __restrict__ VTg, const ushort* __restrict__ S0bf,
        const float* __restrict__ zpart, float* __restrict__ Og) {
    int blk = blockIdx.x;
    int bh = blk / NC, c = blk % NC;
    int b = bh / H, h = bh % H;
    int t0 = c * C;

    __shared__ ushort sQ[C][PQ];        // phi(Q) bf16                 18432 B
    __shared__ ushort sKB[13000];       // phiK[128][PQ] -> Bt[65][PBT] 26000 B
    __shared__ ushort sA[C][C];         // scores, XOR-swizzled         32768 B

    int tid = threadIdx.x;
    int lane = tid & 63;
    int w = tid >> 6;
    int g = lane >> 4, cl = lane & 15;

    const float4* Qg4 = (const float4*)Qg;

    // ---- phase A ----
    for (int l = tid; l < C * 8; l += 512) {        // 2 iters: phi(Q)->LDS
        int i = l >> 3, e8 = l & 7;
        size_t gg = ((size_t)(b * T + t0 + i) * H + h) * 16 + e8 * 2;
        float4 qa = Qg4[gg], qb = Qg4[gg + 1];
        uint4 qv = make_uint4(pk2(phi(qa.x), phi(qa.y)), pk2(phi(qa.z), phi(qa.w)),
                              pk2(phi(qb.x), phi(qb.y)), pk2(phi(qb.z), phi(qb.w)));
        *(uint4*)&sQ[i][e8 * 8] = qv;
    }
    const short8* pk8 = (const short8*)(PKg + (size_t)blk * (C * E));
    for (int l = tid; l < C * 8; l += 512)          // phiK bf16 straight in
        *(short8*)&sKB[(l >> 3) * PQ + (l & 7) * 8] = pk8[l];
    {   // pre-zero sA
        uint4 zz = make_uint4(0, 0, 0, 0);
        ushort* af = (ushort*)sA;
        #pragma unroll
        for (int it = 0; it < 4; ++it)
            *(uint4*)&af[(tid + 512 * it) * 8] = zz;
    }
    const short8* vt8 = (const short8*)(VTg + (size_t)blk * (C * D));
    short8 vt0 = vt8[tid * 2], vt1 = vt8[tid * 2 + 1];
    short8 s0reg = ((const short8*)(S0bf + (size_t)blk * (E * D)))[tid];
    float zreg = (tid < E) ? zpart[(size_t)blk * E + tid] : 0.0f;
    __syncthreads();

    // ---- phase B: scores, lower-triangle tiles; D[m=j][n=i] -> packed store --
    for (int idx = w; idx < 36; idx += 8) {
        int tr = 0;
        while ((tr + 1) * (tr + 2) / 2 <= idx) ++tr;
        int tc = idx - tr * (tr + 1) / 2;
        f32x4 acc = {};
        #pragma unroll
        for (int ks = 0; ks < 2; ++ks) {
            short8 a  = *(const short8*)&sKB[(tc * 16 + cl) * PQ + ks * 32 + g * 8];
            short8 bq = *(const short8*)&sQ[tr * 16 + cl][ks * 32 + g * 8];
            acc = __builtin_amdgcn_mfma_f32_16x16x32_bf16(a, bq, acc, 0, 0, 0);
        }
        int iq = tr * 16 + cl;                  // query row (n)
        int j0 = tc * 16 + g * 4;               // key cols (m), 4 consecutive
        float v0 = (j0 + 0 <= iq) ? acc[0] : 0.0f;
        float v1 = (j0 + 1 <= iq) ? acc[1] : 0.0f;
        float v2 = (j0 + 2 <= iq) ? acc[2] : 0.0f;
        float v3 = (j0 + 3 <= iq) ? acc[3] : 0.0f;
        int pb = (tc * 2 + (g >> 1)) ^ (iq & 7);
        *(uint2*)&sA[iq][pb * 8 + (g & 1) * 4] = make_uint2(pk2(v0, v1), pk2(v2, v3));
    }
    __syncthreads();

    // ---- phase C: Bt = [V^T | S0 ; ones | z] rows in sKB ----
    {
        int i0 = tid * 2, i1 = tid * 2 + 1;      // over [64][16] short8 grid
        *(short8*)&sKB[(i0 >> 4) * PBT + (i0 & 15) * 8] = vt0;
        *(short8*)&sKB[(i1 >> 4) * PBT + (i1 & 15) * 8] = vt1;
        *(short8*)&sKB[(tid >> 3) * PBT + 128 + (tid & 7) * 8] = s0reg;
        if (tid < E) sKB[64 * PBT + 128 + tid] = f2bf(zreg);
        else if (tid < E + 16) {
            short8 ones = {16256, 16256, 16256, 16256, 16256, 16256, 16256, 16256};
            *(short8*)&sKB[64 * PBT + (tid - E) * 8] = ones;
        }
    }
    __syncthreads();

    // ---- phase D: [O|den] = [S|phiQ] @ Bt; wave w owns m-tile perm[w] ----
    {
        const int permv[8] = {0, 1, 2, 3, 6, 7, 4, 5};
        int mt = permv[w];
        int m0 = mt * 16;
        int arow = m0 + cl;
        int aswz = arow & 7;
        int smax = (m0 + 15) >> 5;
        f32x4 acc[5] = {};
        for (int s = 0; s <= smax; ++s) {
            short8 a = *(const short8*)&sA[arow][(((s * 4 + g) ^ aswz)) * 8];
            #pragma unroll
            for (int nt = 0; nt < 5; ++nt) {
                short8 bb = *(const short8*)&sKB[(nt * 16 + cl) * PBT + s * 32 + g * 8];
                acc[nt] = __builtin_amdgcn_mfma_f32_16x16x32_bf16(a, bb, acc[nt], 0, 0, 0);
            }
        }
        #pragma unroll
        for (int s2 = 0; s2 < 2; ++s2) {
            short8 a = *(const short8*)&sQ[arow][s2 * 32 + g * 8];
            #pragma unroll
            for (int nt = 0; nt < 5; ++nt) {
                short8 bb = *(const short8*)&sKB[(nt * 16 + cl) * PBT + 128 + s2 * 32 + g * 8];
                acc[nt] = __builtin_amdgcn_mfma_f32_16x16x32_bf16(a, bb, acc[nt], 0, 0, 0);
            }
        }
        #pragma unroll
        for (int r = 0; r < 4; ++r) {
            float den = __shfl(acc[4][r], lane & 48);   // from lane cl==0 of group
            float zi = 1.0f / (den + EPS);
            int row = m0 + g * 4 + r;
            size_t ga = ((size_t)(b * T + t0 + row) * H + h) * 64;
            #pragma unroll
            for (int nt = 0; nt < 4; ++nt)
                Og[ga + nt * 16 + cl] = acc[nt][r] * zi;
        }
    }
}

extern "C" void kernel_launch(void* const* d_in, const int* in_sizes, int n_in,
                              void* d_out, int out_size, void* d_ws, size_t ws_size,
                              hipStream_t stream) {
    const float* q = (const float*)d_in[0];
    const float* k = (const float*)d_in[1];
    const float* v = (const float*)d_in[2];
    float* out = (float*)d_out;

    float*  SpartT = (float*)d_ws;                             // 8.4 MB
    float*  zpart  = SpartT + (size_t)BH * NC * E * D;         // 128 KB
    ushort* VTg    = (ushort*)(zpart + (size_t)BH * NC * E);   // 8.4 MB
    ushort* PKg    = VTg + (size_t)BH * NC * C * D;            // 8.4 MB
    ushort* S0bf   = PKg + (size_t)BH * NC * C * E;            // 4.2 MB

    k_chunk_sums<<<BH * NC, 256, 0, stream>>>(k, v, SpartT, zpart, VTg, PKg);
    k_scan<<<BH * 17, 256, 0, stream>>>(SpartT, zpart, S0bf);
    k_output<<<BH * NC, 512, 0, stream>>>(q, PKg, VTg, S0bf, zpart, out);
}